// Round 11
// baseline (5053.934 us; speedup 1.0000x reference)
//
#include <hip/hip_runtime.h>

// Problem constants (fixed by the reference).
#define NSTEP 16384   // scan length (== B)
#define NCH   20      // independent chains (== T)
#define D     16      // steps per barrier block
#define NB    (NSTEP / D)   // 1024 blocks
// hidden = 32, gates = 128 per layer (torch order i,f,g,o).

// Raw barrier: order LDS (lgkmcnt) but leave global loads/stores in flight.
#define BAR() asm volatile("s_waitcnt lgkmcnt(0)\n\ts_barrier" ::: "memory")

typedef float v2f __attribute__((ext_vector_type(2)));
typedef unsigned int u32x2 __attribute__((ext_vector_type(2)));

__device__ __forceinline__ float rl(float v, int l) {
  return __builtin_bit_cast(float, __builtin_amdgcn_readlane(__builtin_bit_cast(int, v), l));
}
// Raw transcendentals: v_exp_f32 (2^x) and v_rcp_f32 (~1ulp each).
__device__ __forceinline__ float vexp2(float x) {
  float r; asm("v_exp_f32 %0, %1" : "=v"(r) : "v"(x)); return r;
}
__device__ __forceinline__ float vrcp(float x) {
  float r; asm("v_rcp_f32 %0, %1" : "=v"(r) : "v"(x)); return r;
}
#define KNEG (-1.4426950408889634f)   // -log2(e)

__device__ __forceinline__ float tanhv(float x) {
  // tanh(x) = 2*sigma(2x)-1 ; inf-safe (exp2->inf => rcp->0 => -1).
  const float e = vexp2(x * (2.0f * KNEG));
  return fmaf(2.0f, vrcp(1.0f + e), -1.0f);
}

// Two h-broadcast values packed into one even-aligned SGPR pair.
__device__ __forceinline__ u32x2 rlpair(float v, int k0, int k1) {
  u32x2 r;
  r[0] = (unsigned)__builtin_amdgcn_readlane(__builtin_bit_cast(int, v), k0);
  r[1] = (unsigned)__builtin_amdgcn_readlane(__builtin_bit_cast(int, v), k1);
  return r;
}

// Two packed fp32 FMAs sharing one SGPR pair {h_k, h_k1}:
//   aE.lo += wE.lo*h_k;  aE.hi += wE.hi*h_k;
//   aO.lo += wO.lo*h_k1; aO.hi += wO.hi*h_k1;
// (op_sel_hi[1]=0 -> hi op reads LOW word of src1; op_sel[1]=1 -> low op
// reads HIGH word.) Validated numerically in round 10 (absmax 4.9e-4).
__device__ __forceinline__ void pkfma2(v2f& aE, v2f& aO, v2f wE, v2f wO, u32x2 hs) {
  asm("v_pk_fma_f32 %0, %2, %4, %0 op_sel_hi:[1,0,1]\n\t"
      "v_pk_fma_f32 %1, %3, %4, %1 op_sel:[0,1,0] op_sel_hi:[1,1,1]"
      : "+v"(aE), "+v"(aO)
      : "v"(wE), "v"(wO), "s"(hs));
}

// lane l <-> lane l^32 value exchange on the VALU pipe (v_permlane32_swap).
__device__ __forceinline__ float xswap(float a, bool lower) {
  auto r = __builtin_amdgcn_permlane32_swap(__builtin_bit_cast(int, a),
                                            __builtin_bit_cast(int, a),
                                            false, false);
  return __builtin_bit_cast(float, lower ? r[1] : r[0]);
}

// Keep 8 floats register-resident at this point (no code emitted).
#define PIN8(a, o) asm volatile("" : "+v"(a[o]), "+v"(a[o+1]), "+v"(a[o+2]), \
  "+v"(a[o+3]), "+v"(a[o+4]), "+v"(a[o+5]), "+v"(a[o+6]), "+v"(a[o+7]))

// 4 waves (256 threads), one block per chain n, 1 wave/SIMD.
// Block-pipelined: ONE barrier per D=16 steps. Per-step dot: ALL 32
// v_readlane first (16 SGPR pairs), sched_barrier, then 16 pkfma2 —
// round 10 placed each readlane adjacent to its pk_fma consumer and the
// VALU-writes-SGPR -> VALU-reads-SGPR wait-states sat on the critical
// path (4681us vs round 8's 4434 despite 30% fewer instructions).
// Hoisting puts >=16 instructions between each write and its read.
__global__ __attribute__((amdgpu_flat_work_group_size(256, 256),
                          amdgpu_waves_per_eu(1, 1)))
void lstm2_kernel(const float* __restrict__ x,
                  const float* __restrict__ Wih1, const float* __restrict__ Whh1,
                  const float* __restrict__ bih1, const float* __restrict__ bhh1,
                  const float* __restrict__ Wih2, const float* __restrict__ Whh2,
                  const float* __restrict__ bih2, const float* __restrict__ bhh2,
                  float* __restrict__ ys2)
{
  const int n    = blockIdx.x;
  const int tid  = threadIdx.x;
  const int wave = tid >> 6;
  const int lane = tid & 63;
  const int u    = lane & 31;
  const bool lower = (lane < 32);

  __shared__ __align__(16) float h1s [2][D][32];
  __shared__ __align__(16) float pin1[2][D][128];
  __shared__ __align__(16) float pin2[2][D][128];
  __shared__ __align__(16) float xstage[2][D * 6];   // raw x, one block ahead

  const int r = (wave >= 2) ? (wave - 2) * 64 + lane : 0;   // helper proj row
  // Row gate-scale: g-rows (64..95) get 2*KNEG (tanh via sigma(2x)); else KNEG.
  const float rsHelp = (r >= 64 && r < 96) ? (2.0f * KNEG) : KNEG;
  const float sK = lower ? (2.0f * KNEG) : KNEG;   // scale for w1 rows (g|o)

  // Recurrent waves: wp[k] = (Whh[lane][k]*KNEG, Whh[lane+64][k]*sK).
  v2f wp[32];
#pragma unroll
  for (int k = 0; k < 32; ++k) wp[k] = v2f{0.f, 0.f};
  float w0h[32] = {};      // helpers: Wih2 row (pre-scaled)
  float wI[6] = {};
  float bp1 = 0.f, bp2 = 0.f;

  if (wave == 0) {
#pragma unroll
    for (int k = 0; k < 32; ++k) {
      wp[k] = v2f{Whh1[lane * 32 + k] * KNEG, Whh1[(lane + 64) * 32 + k] * sK};
    }
  } else if (wave == 1) {
#pragma unroll
    for (int k = 0; k < 32; ++k) {
      wp[k] = v2f{Whh2[lane * 32 + k] * KNEG, Whh2[(lane + 64) * 32 + k] * sK};
    }
  } else {
#pragma unroll
    for (int k = 0; k < 32; ++k) w0h[k] = Wih2[r * 32 + k] * rsHelp;
#pragma unroll
    for (int k = 0; k < 6; ++k)  wI[k] = Wih1[r * 6 + k] * rsHelp;
    bp1 = (bih1[r] + bhh1[r]) * rsHelp;
    bp2 = (bih2[r] + bhh2[r]) * rsHelp;
  }

  // Activation affine (branch-free): lane<32 rows (i,g): a1 = 2q-1 (tanh);
  // lane>=32 rows (f,o): a1 = q (sigma). a0 is always sigma.
  const float mA = lower ? 2.0f : 1.0f;
  const float aA = lower ? -1.0f : 0.0f;

  float hval = 0.f, cval = 0.f;

  // ---- prologue: helpers compute pin1 for block 0 (direct global reads)
  //      and stage x of block 1 into xstage[1].
  if (wave >= 2) {
#pragma unroll
    for (int j = 0; j < D; ++j) {
      const float* xp = x + ((size_t)j * NCH + n) * 6;
      const float2 xa = *(const float2*)(xp + 0);
      const float2 xm = *(const float2*)(xp + 2);
      const float2 xc = *(const float2*)(xp + 4);
      float acc = bp1;
      acc = fmaf(xa.x, wI[0], acc); acc = fmaf(xa.y, wI[1], acc);
      acc = fmaf(xm.x, wI[2], acc); acc = fmaf(xm.y, wI[3], acc);
      acc = fmaf(xc.x, wI[4], acc); acc = fmaf(xc.y, wI[5], acc);
      pin1[0][j][r] = acc;
    }
    if (r < D * 6) {
      xstage[1][r] = x[(((size_t)D + r / 6) * NCH + n) * 6 + (r % 6)];
    }
  }

  for (int b = 0; b < NB + 2; ++b) {
    BAR();   // one barrier per D steps; vmcnt never drained in-loop
    const int p = b & 1;

    if (wave < 2) {
      // ---- recurrent waves: wave0 = layer-1 block b; wave1 = layer-2
      //      block b-2 (from pin2). Identical inner bodies.
      const bool active = (wave == 0) ? (b < NB) : (b >= 2);
      if (active) {
        const int t0 = (b - 2) * D;   // wave1 only
        float pa[D], pb[D];
#pragma unroll
        for (int j = 0; j < D; ++j) {
          if (wave == 0) {
            pa[j] = pin1[p][j][lane];
            pb[j] = pin1[p][j][lane + 64];
          } else {
            pa[j] = pin2[p][j][lane];
            pb[j] = pin2[p][j][lane + 64];
          }
        }
        PIN8(pa, 0); PIN8(pa, 8); PIN8(pb, 0); PIN8(pb, 8);
#pragma unroll
        for (int j = 0; j < D; ++j) {
          // Phase 1: ALL broadcasts (32 readlane -> 16 SGPR pairs).
          u32x2 hs[16];
#pragma unroll
          for (int k = 0; k < 16; ++k) hs[k] = rlpair(hval, 2 * k, 2 * k + 1);
          __builtin_amdgcn_sched_barrier(0);   // keep readlanes ahead of FMAs
          // Phase 2: 16 pkfma2 = 32 pk_fma, 4 chains 8 deep.
          v2f ca = v2f{pa[j], pb[j]};
          v2f cb = v2f{0.f, 0.f};
          v2f cc = v2f{0.f, 0.f};
          v2f cd = v2f{0.f, 0.f};
#pragma unroll
          for (int k = 0; k < 16; k += 2) {
            pkfma2(ca, cb, wp[2 * k],     wp[2 * k + 1], hs[k]);
            pkfma2(cc, cd, wp[2 * k + 2], wp[2 * k + 3], hs[k + 1]);
          }
          const v2f s01 = ca + cb;
          const v2f s23 = cc + cd;
          const v2f sum = s01 + s23;
          const float acc0 = sum.x;           // pre-scaled by KNEG
          const float acc1 = sum.y;           // pre-scaled by sK
          const float a0 = vrcp(1.0f + vexp2(acc0));      // sigma (i|f)
          const float q  = vrcp(1.0f + vexp2(acc1));
          const float a1 = fmaf(mA, q, aA);               // tanh(g) | sigma(o)
          const float fv = xswap(a0, lower);
          const float ov = xswap(a1, lower);
          const float ig = a0 * a1;
          // lower lanes hold the true c,h; upper lanes are garbage (never read)
          cval = fmaf(fv, cval, ig);
          hval = ov * tanhv(cval);
          if (wave == 0) {
            if (lower) h1s[p][j][u] = hval;
          } else {
            if (lower) ys2[((size_t)(t0 + j) * NCH + n) * 32 + u] = hval;
          }
        }
      }
    } else {
      // ---- helpers ----
      // (1) issue global x loads for block b+2 (consumed at (4); BAR never
      //     waits vmcnt, latency hidden under (2)+(3)).
      float xr = 0.f;
      const bool doLoad = (r < D * 6) && (b + 2 < NB);
      if (doLoad)
        xr = x[(((size_t)(b + 2) * D + r / 6) * NCH + n) * 6 + (r % 6)];
      // (2) pin2 for block b-1 from h1s (float4 broadcast, 1-ahead prefetch)
      if (b >= 1 && b <= NB) {
        const int q2 = (b - 1) & 1;
        float4 hp[8];
#pragma unroll
        for (int qq = 0; qq < 8; ++qq) hp[qq] = ((const float4*)&h1s[q2][0][0])[qq];
#pragma unroll
        for (int j = 0; j < D; ++j) {
          float4 hn[8];
          if (j + 1 < D) {
#pragma unroll
            for (int qq = 0; qq < 8; ++qq)
              hn[qq] = ((const float4*)&h1s[q2][j + 1][0])[qq];
          }
          float a0 = 0.f, a1 = 0.f, a2 = 0.f, a3 = 0.f;
#pragma unroll
          for (int qq = 0; qq < 8; ++qq) {
            const float4 hv4 = hp[qq];
            a0 = fmaf(hv4.x, w0h[4 * qq + 0], a0);
            a1 = fmaf(hv4.y, w0h[4 * qq + 1], a1);
            a2 = fmaf(hv4.z, w0h[4 * qq + 2], a2);
            a3 = fmaf(hv4.w, w0h[4 * qq + 3], a3);
          }
          pin2[q2][j][r] = bp2 + ((a0 + a1) + (a2 + a3));
          if (j + 1 < D) {
#pragma unroll
            for (int qq = 0; qq < 8; ++qq) hp[qq] = hn[qq];
          }
        }
      }
      // (3) pin1 for block b+1 from xstage (LDS broadcast reads)
      if (b + 1 < NB) {
        const int s2 = (b + 1) & 1;
#pragma unroll
        for (int j = 0; j < D; ++j) {
          const float* xs = &xstage[s2][j * 6];
          const float2 xa = *(const float2*)(xs + 0);
          const float2 xm = *(const float2*)(xs + 2);
          const float2 xc = *(const float2*)(xs + 4);
          float acc = bp1;
          acc = fmaf(xa.x, wI[0], acc); acc = fmaf(xa.y, wI[1], acc);
          acc = fmaf(xm.x, wI[2], acc); acc = fmaf(xm.y, wI[3], acc);
          acc = fmaf(xc.x, wI[4], acc); acc = fmaf(xc.y, wI[5], acc);
          pin1[s2][j][r] = acc;
        }
      }
      // (4) write staged x for block b+2 (waits vmcnt for xr only)
      if (doLoad) xstage[b & 1][r] = xr;
    }
  }
}

// MLP head: z(16384,640) -> relu(640->128) -> relu(128->32) -> 2.
__global__ __launch_bounds__(128, 1)
void head_kernel(const float* __restrict__ ys2,
                 const float* __restrict__ W1, const float* __restrict__ b1,
                 const float* __restrict__ W2, const float* __restrict__ b2,
                 const float* __restrict__ W3, const float* __restrict__ b3,
                 float* __restrict__ out)
{
  const int R = 16;
  const int b0 = blockIdx.x * R;
  const int tid = threadIdx.x;

  __shared__ __align__(16) float zl[R][640];
  __shared__ float z1[R][128];
  __shared__ float z2[R][32];

  {
    const float4* src = (const float4*)(ys2 + (size_t)b0 * 640);
    float4* dst = (float4*)&zl[0][0];
    for (int i = tid; i < R * 160; i += 128) dst[i] = src[i];
  }
  __syncthreads();

  {
    float acc[R];
    const float bb = b1[tid];
#pragma unroll
    for (int r = 0; r < R; ++r) acc[r] = bb;
    for (int kk = 0; kk < 640; kk += 4) {
      const float4 w = *(const float4*)&W1[(size_t)tid * 640 + kk];
#pragma unroll
      for (int r = 0; r < R; ++r) {
        const float4 z4 = *(const float4*)&zl[r][kk];
        acc[r] = fmaf(w.x, z4.x, fmaf(w.y, z4.y, fmaf(w.z, z4.z, fmaf(w.w, z4.w, acc[r]))));
      }
    }
#pragma unroll
    for (int r = 0; r < R; ++r) z1[r][tid] = fmaxf(acc[r], 0.f);
  }
  __syncthreads();

  {
    const int jo = tid & 31, rg = tid >> 5;
    float a2[4];
    const float bb = b2[jo];
#pragma unroll
    for (int q = 0; q < 4; ++q) a2[q] = bb;
    for (int k = 0; k < 128; ++k) {
      const float w = W2[jo * 128 + k];
#pragma unroll
      for (int q = 0; q < 4; ++q) a2[q] = fmaf(w, z1[rg + 4 * q][k], a2[q]);
    }
#pragma unroll
    for (int q = 0; q < 4; ++q) z2[rg + 4 * q][jo] = fmaxf(a2[q], 0.f);
  }
  __syncthreads();

  if (tid < 32) {
    const int r = tid >> 1, jo = tid & 1;
    float a = b3[jo];
#pragma unroll
    for (int k = 0; k < 32; ++k) a = fmaf(W3[jo * 32 + k], z2[r][k], a);
    out[(size_t)(b0 + r) * 2 + jo] = a;
  }
}

extern "C" void kernel_launch(void* const* d_in, const int* in_sizes, int n_in,
                              void* d_out, int out_size, void* d_ws, size_t ws_size,
                              hipStream_t stream) {
  (void)in_sizes; (void)n_in; (void)out_size; (void)ws_size;
  const float* x    = (const float*)d_in[0];
  const float* Wih1 = (const float*)d_in[1];
  const float* Whh1 = (const float*)d_in[2];
  const float* bih1 = (const float*)d_in[3];
  const float* bhh1 = (const float*)d_in[4];
  const float* Wih2 = (const float*)d_in[5];
  const float* Whh2 = (const float*)d_in[6];
  const float* bih2 = (const float*)d_in[7];
  const float* bhh2 = (const float*)d_in[8];
  const float* W1   = (const float*)d_in[9];
  const float* b1   = (const float*)d_in[10];
  const float* W2   = (const float*)d_in[11];
  const float* b2   = (const float*)d_in[12];
  const float* W3   = (const float*)d_in[13];
  const float* b3   = (const float*)d_in[14];
  float* out = (float*)d_out;

  float* ys2 = (float*)d_ws;   // (16384, 20, 32) fp32 = 41.9 MB

  lstm2_kernel<<<NCH, 256, 0, stream>>>(x, Wih1, Whh1, bih1, bhh1,
                                        Wih2, Whh2, bih2, bhh2, ys2);
  head_kernel<<<NSTEP / 16, 128, 0, stream>>>(ys2, W1, b1, W2, b2, W3, b3, out);
}

// Round 13
// 4232.119 us; speedup vs baseline: 1.1942x; 1.1942x over previous
//
#include <hip/hip_runtime.h>

// Problem constants (fixed by the reference).
#define NSTEP 16384   // scan length (== B)
#define NCH   20      // independent chains (== T)
#define D     16      // steps per barrier block
#define NB    (NSTEP / D)   // 1024 blocks
// hidden = 32, gates = 128 per layer (torch order i,f,g,o).

// Raw barrier: order LDS (lgkmcnt) but leave global loads/stores in flight.
#define BAR() asm volatile("s_waitcnt lgkmcnt(0)\n\ts_barrier" ::: "memory")

typedef _Float16 h2 __attribute__((ext_vector_type(2)));

// Raw transcendentals: v_exp_f32 (2^x) and v_rcp_f32 (~1ulp each).
__device__ __forceinline__ float vexp2(float x) {
  float r; asm("v_exp_f32 %0, %1" : "=v"(r) : "v"(x)); return r;
}
__device__ __forceinline__ float vrcp(float x) {
  float r; asm("v_rcp_f32 %0, %1" : "=v"(r) : "v"(x)); return r;
}
#define KNEG (-1.4426950408889634f)   // -log2(e)

// Uniform (SGPR) packed fp16 h-pair pulled from even lane 2k.
__device__ __forceinline__ h2 rlh(unsigned hpku, int srclane) {
  return __builtin_bit_cast(h2,
      (unsigned)__builtin_amdgcn_readlane((int)hpku, srclane));
}

// lane l <-> lane l^32 value exchange on the VALU pipe (v_permlane32_swap).
__device__ __forceinline__ float xswap(float a, bool lower) {
  auto r = __builtin_amdgcn_permlane32_swap(__builtin_bit_cast(int, a),
                                            __builtin_bit_cast(int, a),
                                            false, false);
  return __builtin_bit_cast(float, lower ? r[1] : r[0]);
}

// Keep 8 floats register-resident at this point (no code emitted).
#define PIN8(a, o) asm volatile("" : "+v"(a[o]), "+v"(a[o+1]), "+v"(a[o+2]), \
  "+v"(a[o+3]), "+v"(a[o+4]), "+v"(a[o+5]), "+v"(a[o+6]), "+v"(a[o+7]))

// 4 waves (256 threads), one block per chain n, 1 wave/SIMD.
// Block-pipelined: ONE barrier per D=16 steps (round-8 structure, best
// known). This round: recurrent dot in fp16-pair MACs (v_dot2_f32_f16,
// full-rate DL op) — 32 fdot2 replace 64 v_fma, and the h-broadcast packs
// (h_2j,h_2j+1) in-lane (DPP neighbor + cvt_pkrtz) so only 16 readlanes
// replace 32. pk_fma rounds (10/11) proved VOP3P packed-f32 is NOT
// full-rate on gfx950 — fdot2 is the 2-MAC-per-pass op.
__global__ __attribute__((amdgpu_flat_work_group_size(256, 256),
                          amdgpu_waves_per_eu(1, 1)))
void lstm2_kernel(const float* __restrict__ x,
                  const float* __restrict__ Wih1, const float* __restrict__ Whh1,
                  const float* __restrict__ bih1, const float* __restrict__ bhh1,
                  const float* __restrict__ Wih2, const float* __restrict__ Whh2,
                  const float* __restrict__ bih2, const float* __restrict__ bhh2,
                  float* __restrict__ ys2)
{
  const int n    = blockIdx.x;
  const int tid  = threadIdx.x;
  const int wave = tid >> 6;
  const int lane = tid & 63;
  const int u    = lane & 31;
  const bool lower = (lane < 32);

  __shared__ __align__(16) float h1s [2][D][32];
  __shared__ __align__(16) float pin1[2][D][128];
  __shared__ __align__(16) float pin2[2][D][128];
  __shared__ __align__(16) float xstage[2][D * 6];   // raw x, one block ahead

  const int r = (wave >= 2) ? (wave - 2) * 64 + lane : 0;   // helper proj row
  // Row gate-scale: g-rows (64..95) get 2*KNEG (tanh via sigma(2x)); else KNEG.
  const float rsHelp = (r >= 64 && r < 96) ? (2.0f * KNEG) : KNEG;
  const float sK = lower ? (2.0f * KNEG) : KNEG;   // scale for row-B (g|o)

  // Recurrent waves: fp16 pair weights, pre-scaled.
  // wA[k] = (W[lane][2k],W[lane][2k+1])*KNEG ; wB: row lane+64, scale sK.
  h2 wA[16], wB[16];
#pragma unroll
  for (int k = 0; k < 16; ++k) { wA[k] = h2{0, 0}; wB[k] = h2{0, 0}; }
  float w0h[32] = {};      // helpers: Wih2 row (pre-scaled, fp32)
  float wI[6] = {};
  float bp1 = 0.f, bp2 = 0.f;

  if (wave < 2) {
    const float* Whh = (wave == 0) ? Whh1 : Whh2;
#pragma unroll
    for (int k = 0; k < 16; ++k) {
      wA[k] = h2{(_Float16)(Whh[lane * 32 + 2 * k] * KNEG),
                 (_Float16)(Whh[lane * 32 + 2 * k + 1] * KNEG)};
      wB[k] = h2{(_Float16)(Whh[(lane + 64) * 32 + 2 * k] * sK),
                 (_Float16)(Whh[(lane + 64) * 32 + 2 * k + 1] * sK)};
    }
  } else {
#pragma unroll
    for (int k = 0; k < 32; ++k) w0h[k] = Wih2[r * 32 + k] * rsHelp;
#pragma unroll
    for (int k = 0; k < 6; ++k)  wI[k] = Wih1[r * 6 + k] * rsHelp;
    bp1 = (bih1[r] + bhh1[r]) * rsHelp;
    bp2 = (bih2[r] + bhh2[r]) * rsHelp;
  }

  // Activation affine (branch-free). a0 = sigma always. Row B: lower (g):
  // a1s = 2K*tanh = fmaf(4K, q, -2K)  (pre-scaled for the c' = 2K*c track);
  // upper (o): a1 = q = sigma.
  const float mA2 = lower ? (4.0f * KNEG) : 1.0f;
  const float aA2 = lower ? (-2.0f * KNEG) : 0.0f;

  float hval = 0.f, cval = 0.f;   // cval is c' = 2K*c (scaled track)

  // ---- prologue: helpers compute pin1 for block 0 (direct global reads)
  //      and stage x of block 1 into xstage[1].
  if (wave >= 2) {
#pragma unroll
    for (int j = 0; j < D; ++j) {
      const float* xp = x + ((size_t)j * NCH + n) * 6;
      const float2 xa = *(const float2*)(xp + 0);
      const float2 xm = *(const float2*)(xp + 2);
      const float2 xc = *(const float2*)(xp + 4);
      float acc = bp1;
      acc = fmaf(xa.x, wI[0], acc); acc = fmaf(xa.y, wI[1], acc);
      acc = fmaf(xm.x, wI[2], acc); acc = fmaf(xm.y, wI[3], acc);
      acc = fmaf(xc.x, wI[4], acc); acc = fmaf(xc.y, wI[5], acc);
      pin1[0][j][r] = acc;
    }
    if (r < D * 6) {
      xstage[1][r] = x[(((size_t)D + r / 6) * NCH + n) * 6 + (r % 6)];
    }
  }

  for (int b = 0; b < NB + 2; ++b) {
    BAR();   // one barrier per D steps; vmcnt never drained in-loop
    const int p = b & 1;

    if (wave < 2) {
      // ---- recurrent waves: wave0 = layer-1 block b; wave1 = layer-2
      //      block b-2 (from pin2). Identical inner bodies.
      const bool active = (wave == 0) ? (b < NB) : (b >= 2);
      if (active) {
        const int t0 = (b - 2) * D;   // wave1 only
        float pa[D], pb[D];
#pragma unroll
        for (int j = 0; j < D; ++j) {
          if (wave == 0) {
            pa[j] = pin1[p][j][lane];
            pb[j] = pin1[p][j][lane + 64];
          } else {
            pa[j] = pin2[p][j][lane];
            pb[j] = pin2[p][j][lane + 64];
          }
        }
        PIN8(pa, 0); PIN8(pa, 8); PIN8(pb, 0); PIN8(pb, 8);
#pragma unroll
        for (int j = 0; j < D; ++j) {
          // In-lane fp16 pair pack: neighbor h (DPP quad_perm [1,0,3,2])
          // + cvt_pkrtz -> even lane 2j holds (h_2j, h_2j+1) packed.
          const int nbh = __builtin_amdgcn_update_dpp(
              __builtin_bit_cast(int, hval), __builtin_bit_cast(int, hval),
              0xB1, 0xF, 0xF, true);
          const unsigned hpku = __builtin_bit_cast(unsigned,
              __builtin_amdgcn_cvt_pkrtz(hval, __builtin_bit_cast(float, nbh)));
          // Dot: 4 chains x 8 fdot2 (2 MACs each) = full 32-dot x 2 rows.
          float c0a = pa[j], c0b = 0.f;
          float c1a = pb[j], c1b = 0.f;
#pragma unroll
          for (int kk = 0; kk < 16; kk += 2) {
            const h2 hA = rlh(hpku, 2 * kk);
            const h2 hB = rlh(hpku, 2 * kk + 2);
            c0a = __builtin_amdgcn_fdot2(wA[kk],     hA, c0a, false);
            c1a = __builtin_amdgcn_fdot2(wB[kk],     hA, c1a, false);
            c0b = __builtin_amdgcn_fdot2(wA[kk + 1], hB, c0b, false);
            c1b = __builtin_amdgcn_fdot2(wB[kk + 1], hB, c1b, false);
          }
          const float acc0 = c0a + c0b;       // pre-scaled by KNEG
          const float acc1 = c1a + c1b;       // pre-scaled by sK
          const float a0 = vrcp(1.0f + vexp2(acc0));      // sigma (i|f)
          const float q  = vrcp(1.0f + vexp2(acc1));
          const float a1 = fmaf(mA2, q, aA2);  // lower: 2K*tanh(g); upper: sigma(o)
          const float fv = xswap(a0, lower);
          const float ov = xswap(a1, lower);
          const float ig = a0 * a1;            // lower: sigma(i)*2K*tanh(g)
          // c' = 2K*c: c' = f*c' + 2K*i*g ; tanh(c) = 2*rcp(1+exp2(c'))-1
          cval = fmaf(fv, cval, ig);
          const float q2 = vrcp(1.0f + vexp2(cval));
          hval = fmaf(2.0f * ov, q2, -ov);
          if (wave == 0) {
            if (lower) h1s[p][j][u] = hval;
          } else {
            if (lower) ys2[((size_t)(t0 + j) * NCH + n) * 32 + u] = hval;
          }
        }
      }
    } else {
      // ---- helpers ----
      // (1) issue global x loads for block b+2 (consumed at (4); BAR never
      //     waits vmcnt, latency hidden under (2)+(3)).
      float xr = 0.f;
      const bool doLoad = (r < D * 6) && (b + 2 < NB);
      if (doLoad)
        xr = x[(((size_t)(b + 2) * D + r / 6) * NCH + n) * 6 + (r % 6)];
      // (2) pin2 for block b-1 from h1s (float4 broadcast, 1-ahead prefetch)
      if (b >= 1 && b <= NB) {
        const int q2 = (b - 1) & 1;
        float4 hp[8];
#pragma unroll
        for (int qq = 0; qq < 8; ++qq) hp[qq] = ((const float4*)&h1s[q2][0][0])[qq];
#pragma unroll
        for (int j = 0; j < D; ++j) {
          float4 hn[8];
          if (j + 1 < D) {
#pragma unroll
            for (int qq = 0; qq < 8; ++qq)
              hn[qq] = ((const float4*)&h1s[q2][j + 1][0])[qq];
          }
          float a0 = 0.f, a1 = 0.f, a2 = 0.f, a3 = 0.f;
#pragma unroll
          for (int qq = 0; qq < 8; ++qq) {
            const float4 hv4 = hp[qq];
            a0 = fmaf(hv4.x, w0h[4 * qq + 0], a0);
            a1 = fmaf(hv4.y, w0h[4 * qq + 1], a1);
            a2 = fmaf(hv4.z, w0h[4 * qq + 2], a2);
            a3 = fmaf(hv4.w, w0h[4 * qq + 3], a3);
          }
          pin2[q2][j][r] = bp2 + ((a0 + a1) + (a2 + a3));
          if (j + 1 < D) {
#pragma unroll
            for (int qq = 0; qq < 8; ++qq) hp[qq] = hn[qq];
          }
        }
      }
      // (3) pin1 for block b+1 from xstage (LDS broadcast reads)
      if (b + 1 < NB) {
        const int s2 = (b + 1) & 1;
#pragma unroll
        for (int j = 0; j < D; ++j) {
          const float* xs = &xstage[s2][j * 6];
          const float2 xa = *(const float2*)(xs + 0);
          const float2 xm = *(const float2*)(xs + 2);
          const float2 xc = *(const float2*)(xs + 4);
          float acc = bp1;
          acc = fmaf(xa.x, wI[0], acc); acc = fmaf(xa.y, wI[1], acc);
          acc = fmaf(xm.x, wI[2], acc); acc = fmaf(xm.y, wI[3], acc);
          acc = fmaf(xc.x, wI[4], acc); acc = fmaf(xc.y, wI[5], acc);
          pin1[s2][j][r] = acc;
        }
      }
      // (4) write staged x for block b+2 (waits vmcnt for xr only)
      if (doLoad) xstage[b & 1][r] = xr;
    }
  }
}

// MLP head: z(16384,640) -> relu(640->128) -> relu(128->32) -> 2.
__global__ __launch_bounds__(128, 1)
void head_kernel(const float* __restrict__ ys2,
                 const float* __restrict__ W1, const float* __restrict__ b1,
                 const float* __restrict__ W2, const float* __restrict__ b2,
                 const float* __restrict__ W3, const float* __restrict__ b3,
                 float* __restrict__ out)
{
  const int R = 16;
  const int b0 = blockIdx.x * R;
  const int tid = threadIdx.x;

  __shared__ __align__(16) float zl[R][640];
  __shared__ float z1[R][128];
  __shared__ float z2[R][32];

  {
    const float4* src = (const float4*)(ys2 + (size_t)b0 * 640);
    float4* dst = (float4*)&zl[0][0];
    for (int i = tid; i < R * 160; i += 128) dst[i] = src[i];
  }
  __syncthreads();

  {
    float acc[R];
    const float bb = b1[tid];
#pragma unroll
    for (int r = 0; r < R; ++r) acc[r] = bb;
    for (int kk = 0; kk < 640; kk += 4) {
      const float4 w = *(const float4*)&W1[(size_t)tid * 640 + kk];
#pragma unroll
      for (int r = 0; r < R; ++r) {
        const float4 z4 = *(const float4*)&zl[r][kk];
        acc[r] = fmaf(w.x, z4.x, fmaf(w.y, z4.y, fmaf(w.z, z4.z, fmaf(w.w, z4.w, acc[r]))));
      }
    }
#pragma unroll
    for (int r = 0; r < R; ++r) z1[r][tid] = fmaxf(acc[r], 0.f);
  }
  __syncthreads();

  {
    const int jo = tid & 31, rg = tid >> 5;
    float a2[4];
    const float bb = b2[jo];
#pragma unroll
    for (int q = 0; q < 4; ++q) a2[q] = bb;
    for (int k = 0; k < 128; ++k) {
      const float w = W2[jo * 128 + k];
#pragma unroll
      for (int q = 0; q < 4; ++q) a2[q] = fmaf(w, z1[rg + 4 * q][k], a2[q]);
    }
#pragma unroll
    for (int q = 0; q < 4; ++q) z2[rg + 4 * q][jo] = fmaxf(a2[q], 0.f);
  }
  __syncthreads();

  if (tid < 32) {
    const int r = tid >> 1, jo = tid & 1;
    float a = b3[jo];
#pragma unroll
    for (int k = 0; k < 32; ++k) a = fmaf(W3[jo * 32 + k], z2[r][k], a);
    out[(size_t)(b0 + r) * 2 + jo] = a;
  }
}

extern "C" void kernel_launch(void* const* d_in, const int* in_sizes, int n_in,
                              void* d_out, int out_size, void* d_ws, size_t ws_size,
                              hipStream_t stream) {
  (void)in_sizes; (void)n_in; (void)out_size; (void)ws_size;
  const float* x    = (const float*)d_in[0];
  const float* Wih1 = (const float*)d_in[1];
  const float* Whh1 = (const float*)d_in[2];
  const float* bih1 = (const float*)d_in[3];
  const float* bhh1 = (const float*)d_in[4];
  const float* Wih2 = (const float*)d_in[5];
  const float* Whh2 = (const float*)d_in[6];
  const float* bih2 = (const float*)d_in[7];
  const float* bhh2 = (const float*)d_in[8];
  const float* W1   = (const float*)d_in[9];
  const float* b1   = (const float*)d_in[10];
  const float* W2   = (const float*)d_in[11];
  const float* b2   = (const float*)d_in[12];
  const float* W3   = (const float*)d_in[13];
  const float* b3   = (const float*)d_in[14];
  float* out = (float*)d_out;

  float* ys2 = (float*)d_ws;   // (16384, 20, 32) fp32 = 41.9 MB

  lstm2_kernel<<<NCH, 256, 0, stream>>>(x, Wih1, Whh1, bih1, bhh1,
                                        Wih2, Whh2, bih2, bhh2, ys2);
  head_kernel<<<NSTEP / 16, 128, 0, stream>>>(ys2, W1, b1, W2, b2, W3, b3, out);
}